// Round 3
// baseline (1058.363 us; speedup 1.0000x reference)
//
#include <hip/hip_runtime.h>

// AttnHGCN.forward_ui — 3-layer bipartite LightGCN-style propagation.
// R3: (a) CSR slots packed as int2 (one 8B random store per directed edge
//     instead of two 4B stores — R2 showed 368 MB HBM write amplification),
//     (b) residual accumulate + final scale fused into the gather epilogue,
//     (c) layer 1 gathers straight from input tables; no init memcpys.

constexpr int N_USERS = 100000;
constexpr int N_ITEMS = 50000;
constexpr int CH      = 64;
constexpr int N_EDGES = 2000000;
constexpr int LAYERS  = 3;
constexpr int NROWS   = N_USERS + N_ITEMS;          // 150000 combined dest rows
constexpr int NDIR    = 2 * N_EDGES;                // 4M directed edges

constexpr long long ITEM_ELEMS = (long long)N_ITEMS * CH;  // 3,200,000
constexpr long long USER_ELEMS = (long long)N_USERS * CH;  // 6,400,000
constexpr long long TOT_ELEMS  = ITEM_ELEMS + USER_ELEMS;  // 9,600,000

// ---------------- CSR build ----------------

__global__ __launch_bounds__(256) void hist_kernel(
    const int* __restrict__ u_idx, const int* __restrict__ i_idx,
    int* __restrict__ counts) {
  int e = blockIdx.x * 256 + threadIdx.x;
  if (e >= N_EDGES) return;
  atomicAdd(&counts[u_idx[e]], 1);            // user rows: 0..N_USERS-1
  atomicAdd(&counts[N_USERS + i_idx[e]], 1);  // item rows: N_USERS..NROWS-1
}

// per-256-block exclusive scan; block sums out
__global__ __launch_bounds__(256) void scanA_kernel(
    const int* __restrict__ counts, int* __restrict__ row_ptr,
    int* __restrict__ blksums, int n) {
  __shared__ int sh[256];
  int t = threadIdx.x;
  int i = blockIdx.x * 256 + t;
  int v = (i < n) ? counts[i] : 0;
  int x = v;
  sh[t] = x; __syncthreads();
  for (int d = 1; d < 256; d <<= 1) {
    int add = (t >= d) ? sh[t - d] : 0;
    __syncthreads();
    x += add; sh[t] = x;
    __syncthreads();
  }
  if (i < n) row_ptr[i] = x - v;  // exclusive within block
  if (t == 255) blksums[blockIdx.x] = x;
}

// single-block exclusive scan of block sums (n2 <= 1024)
__global__ __launch_bounds__(1024) void scanB_kernel(int* __restrict__ blksums, int n2) {
  __shared__ int sh[1024];
  int t = threadIdx.x;
  int v = (t < n2) ? blksums[t] : 0;
  int x = v;
  sh[t] = x; __syncthreads();
  for (int d = 1; d < 1024; d <<= 1) {
    int add = (t >= d) ? sh[t - d] : 0;
    __syncthreads();
    x += add; sh[t] = x;
    __syncthreads();
  }
  if (t < n2) blksums[t] = x - v;  // exclusive
}

// add block offsets; init cursor; set terminator
__global__ __launch_bounds__(256) void scanC_kernel(
    int* __restrict__ row_ptr, const int* __restrict__ blksums,
    int* __restrict__ cursor, int n) {
  int i = blockIdx.x * 256 + threadIdx.x;
  if (i < n) {
    int p = row_ptr[i] + blksums[i >> 8];
    row_ptr[i] = p;
    cursor[i] = p;
  }
  if (i == 0) row_ptr[n] = NDIR;
}

// scatter edges into packed CSR slots: one 8B store per directed edge
__global__ __launch_bounds__(256) void scatter_csr_kernel(
    const int* __restrict__ u_idx, const int* __restrict__ i_idx,
    const float* __restrict__ w, int* __restrict__ cursor,
    int2* __restrict__ csr) {
  int e = blockIdx.x * 256 + threadIdx.x;
  if (e >= N_EDGES) return;
  int u = u_idx[e], it = i_idx[e];
  int wb = __float_as_int(w[e]);
  int pu = atomicAdd(&cursor[u], 1);
  int pi = atomicAdd(&cursor[N_USERS + it], 1);
  csr[pu] = make_int2(it, wb);  // user row gathers item rows
  csr[pi] = make_int2(u, wb);   // item row gathers user rows
}

// ---------------- per-layer fused gather ----------------
// One wave per destination row; lane = slot(2b) x chan16(4b); 4 edges in
// flight, butterfly-reduce slots. Epilogue fuses residual accumulation:
//   MODE 0 (layer 1):   dst = acc;  out = emb + acc
//   MODE 1 (mid layer): dst = acc;  out += acc
//   MODE 2 (last):                  out = (out + acc) * 1/(LAYERS+1)
template <int MODE>
__global__ __launch_bounds__(256) void gather_fused(
    const float* __restrict__ it_tab,  // gather-source item table
    const float* __restrict__ u_tab,   // gather-source user table
    float* __restrict__ dst,           // [it|u] layer output (MODE<2)
    float* __restrict__ out,           // [item_acc | user_acc]
    const int2* __restrict__ csr,
    const int* __restrict__ row_ptr) {
  int row = blockIdx.x * 4 + (threadIdx.x >> 6);
  if (row >= NROWS) return;
  int lane = threadIdx.x & 63;
  int slot = lane >> 4;          // 0..3
  int c4   = (lane & 15) * 4;    // channel offset 0..60

  const float* gtab;             // opposite-side table to gather from
  const float* erow = nullptr;   // dest-side input-emb row (MODE 0)
  float* drow = nullptr;
  float* orow;
  if (row < N_USERS) {
    gtab = it_tab;
    orow = out + ITEM_ELEMS + (long long)row * CH;
    if (MODE < 2)  drow = dst + ITEM_ELEMS + (long long)row * CH;
    if (MODE == 0) erow = u_tab + (long long)row * CH;  // u_tab==user_emb here
  } else {
    int r = row - N_USERS;
    gtab = u_tab;
    orow = out + (long long)r * CH;
    if (MODE < 2)  drow = dst + (long long)r * CH;
    if (MODE == 0) erow = it_tab + (long long)r * CH;   // it_tab==item_emb here
  }

  int beg = row_ptr[row], end = row_ptr[row + 1];
  float4 acc = make_float4(0.f, 0.f, 0.f, 0.f);
  for (int j = beg + slot; j < end; j += 4) {
    int2  e  = csr[j];
    float we = __int_as_float(e.y);
    float4 v = *(const float4*)(gtab + (long long)e.x * CH + c4);
    acc.x += we * v.x; acc.y += we * v.y;
    acc.z += we * v.z; acc.w += we * v.w;
  }
  for (int off = 16; off < 64; off <<= 1) {
    acc.x += __shfl_xor(acc.x, off, 64);
    acc.y += __shfl_xor(acc.y, off, 64);
    acc.z += __shfl_xor(acc.z, off, 64);
    acc.w += __shfl_xor(acc.w, off, 64);
  }
  if (slot == 0) {
    if (MODE == 0) {
      float4 e4 = *(const float4*)(erow + c4);
      *(float4*)(drow + c4) = acc;
      e4.x += acc.x; e4.y += acc.y; e4.z += acc.z; e4.w += acc.w;
      *(float4*)(orow + c4) = e4;
    } else if (MODE == 1) {
      float4 o = *(const float4*)(orow + c4);
      *(float4*)(drow + c4) = acc;
      o.x += acc.x; o.y += acc.y; o.z += acc.z; o.w += acc.w;
      *(float4*)(orow + c4) = o;
    } else {
      const float s = 1.0f / (LAYERS + 1);
      float4 o = *(const float4*)(orow + c4);
      o.x = (o.x + acc.x) * s; o.y = (o.y + acc.y) * s;
      o.z = (o.z + acc.z) * s; o.w = (o.w + acc.w) * s;
      *(float4*)(orow + c4) = o;
    }
  }
}

// ---------------- fallback (R1 atomic path) ----------------

__global__ __launch_bounds__(256) void atomic_scatter_kernel(
    const float* __restrict__ src, float* __restrict__ dst,
    const int* __restrict__ u_idx, const int* __restrict__ i_idx,
    const float* __restrict__ w) {
  long long tid = (long long)blockIdx.x * blockDim.x + threadIdx.x;
  int edge = (int)(tid >> 4);
  if (edge >= N_EDGES) return;
  int c = ((int)tid & 15) * 4;
  int ui = u_idx[edge], ii = i_idx[edge];
  float we = w[edge];
  float4 itv = *(const float4*)(src + (long long)ii * CH + c);
  float4 uv  = *(const float4*)(src + ITEM_ELEMS + (long long)ui * CH + c);
  float* ud = dst + ITEM_ELEMS + (long long)ui * CH + c;
  float* id = dst + (long long)ii * CH + c;
  unsafeAtomicAdd(ud + 0, we * itv.x);
  unsafeAtomicAdd(ud + 1, we * itv.y);
  unsafeAtomicAdd(ud + 2, we * itv.z);
  unsafeAtomicAdd(ud + 3, we * itv.w);
  unsafeAtomicAdd(id + 0, we * uv.x);
  unsafeAtomicAdd(id + 1, we * uv.y);
  unsafeAtomicAdd(id + 2, we * uv.z);
  unsafeAtomicAdd(id + 3, we * uv.w);
}

__global__ __launch_bounds__(256) void add_scale_kernel(
    float* __restrict__ acc, const float* __restrict__ add, float s, long long n4) {
  long long i = (long long)blockIdx.x * blockDim.x + threadIdx.x;
  if (i >= n4) return;
  float4 a = ((const float4*)acc)[i];
  float4 b = ((const float4*)add)[i];
  a.x = (a.x + b.x) * s;
  a.y = (a.y + b.y) * s;
  a.z = (a.z + b.z) * s;
  a.w = (a.w + b.w) * s;
  ((float4*)acc)[i] = a;
}

extern "C" void kernel_launch(void* const* d_in, const int* in_sizes, int n_in,
                              void* d_out, int out_size, void* d_ws, size_t ws_size,
                              hipStream_t stream) {
  const float* user_emb = (const float*)d_in[1];
  const float* item_emb = (const float*)d_in[2];
  const int*   edges    = (const int*)d_in[3];
  const int*   u_idx    = edges;            // row 0
  const int*   i_idx    = edges + N_EDGES;  // row 1
  const float* w        = (const float*)d_in[4];

  float* out = (float*)d_out;  // [item_acc | user_acc]

  // workspace layout (4B units)
  float* buf_a   = (float*)d_ws;                 // TOT_ELEMS
  float* buf_b   = buf_a + TOT_ELEMS;            // TOT_ELEMS
  int2*  csr     = (int2*)(buf_b + TOT_ELEMS);   // NDIR int2
  int*   counts  = (int*)(csr + NDIR);           // NROWS
  int*   row_ptr = counts + NROWS;               // NROWS + 1
  int*   cursor  = row_ptr + NROWS + 1;          // NROWS
  int*   blksums = cursor + NROWS;               // 1024
  const size_t needed =
      ((size_t)2 * TOT_ELEMS + 2 * (size_t)NDIR + 3 * (size_t)NROWS + 1 + 1024) * 4;

  const int edge_blocks = (N_EDGES + 255) / 256;

  if (ws_size >= needed) {
    // ---- CSR build (once per call) ----
    hipMemsetAsync(counts, 0, (size_t)NROWS * sizeof(int), stream);
    hist_kernel<<<edge_blocks, 256, 0, stream>>>(u_idx, i_idx, counts);
    const int nblocksA = (NROWS + 255) / 256;  // 587 <= 1024
    scanA_kernel<<<nblocksA, 256, 0, stream>>>(counts, row_ptr, blksums, NROWS);
    scanB_kernel<<<1, 1024, 0, stream>>>(blksums, nblocksA);
    scanC_kernel<<<nblocksA, 256, 0, stream>>>(row_ptr, blksums, cursor, NROWS);
    scatter_csr_kernel<<<edge_blocks, 256, 0, stream>>>(u_idx, i_idx, w, cursor, csr);

    // ---- layers (gather + fused residual) ----
    const int gather_blocks = (NROWS + 3) / 4;  // 4 rows (waves) per block
    // L1: gather from input tables; out = emb + l1; buf_a = l1
    gather_fused<0><<<gather_blocks, 256, 0, stream>>>(
        item_emb, user_emb, buf_a, out, csr, row_ptr);
    // L2: gather from buf_a; out += l2; buf_b = l2
    gather_fused<1><<<gather_blocks, 256, 0, stream>>>(
        buf_a, buf_a + ITEM_ELEMS, buf_b, out, csr, row_ptr);
    // L3: gather from buf_b; out = (out + l3) * 0.25
    gather_fused<2><<<gather_blocks, 256, 0, stream>>>(
        buf_b, buf_b + ITEM_ELEMS, nullptr, out, csr, row_ptr);
  } else {
    // ---- fallback: R1 atomic scatter ----
    const size_t item_bytes = (size_t)ITEM_ELEMS * sizeof(float);
    const size_t user_bytes = (size_t)USER_ELEMS * sizeof(float);
    hipMemcpyAsync(buf_a,              item_emb, item_bytes, hipMemcpyDeviceToDevice, stream);
    hipMemcpyAsync(buf_a + ITEM_ELEMS, user_emb, user_bytes, hipMemcpyDeviceToDevice, stream);
    hipMemcpyAsync(out,                item_emb, item_bytes, hipMemcpyDeviceToDevice, stream);
    hipMemcpyAsync(out + ITEM_ELEMS,   user_emb, user_bytes, hipMemcpyDeviceToDevice, stream);
    const long long st = (long long)N_EDGES * 16;
    const int sb = (int)((st + 255) / 256);
    const long long n4 = TOT_ELEMS / 4;
    const int add_blocks = (int)((n4 + 255) / 256);
    float* src = buf_a;
    float* dst = buf_b;
    for (int l = 0; l < LAYERS; ++l) {
      hipMemsetAsync(dst, 0, (size_t)TOT_ELEMS * sizeof(float), stream);
      atomic_scatter_kernel<<<sb, 256, 0, stream>>>(src, dst, u_idx, i_idx, w);
      const float s = (l == LAYERS - 1) ? (1.0f / (LAYERS + 1)) : 1.0f;
      add_scale_kernel<<<add_blocks, 256, 0, stream>>>(out, dst, s, n4);
      float* t = src; src = dst; dst = t;
    }
  }
}

// Round 4
// 894.263 us; speedup vs baseline: 1.1835x; 1.1835x over previous
//
#include <hip/hip_runtime.h>

// AttnHGCN.forward_ui — 3-layer bipartite LightGCN-style propagation.
// R4: windowed CSR scatter. R3 post-mortem showed the CSR-build scatter is
// LATENCY-bound with full-line (64B) dirty-writeback per random 8B store
// (WRITE_SIZE 248MB for 32MB payload). Fix: (a) partition dest rows into 8
// windows (~4MB of CSR slots each) processed in blockIdx order within ONE
// dispatch, so same-line stores cluster temporally and coalesce in L2;
// (b) 4 edges/thread with int4/float4 loads -> 8 independent atomics + 8
// independent stores in flight (R3 regression traced to MLP loss, 4->2).

constexpr int N_USERS = 100000;
constexpr int N_ITEMS = 50000;
constexpr int CH      = 64;
constexpr int N_EDGES = 2000000;
constexpr int LAYERS  = 3;
constexpr int NROWS   = N_USERS + N_ITEMS;          // 150000 combined dest rows
constexpr int NDIR    = 2 * N_EDGES;                // 4M directed edges

constexpr int PASSES  = 8;
constexpr int WROWS   = NROWS / PASSES;             // 18750 rows per window
constexpr int QEDGES  = N_EDGES / 4;                // 500000 int4 edge-quads
constexpr int BPP     = (QEDGES + 255) / 256;       // blocks per pass = 1954

constexpr long long ITEM_ELEMS = (long long)N_ITEMS * CH;  // 3,200,000
constexpr long long USER_ELEMS = (long long)N_USERS * CH;  // 6,400,000
constexpr long long TOT_ELEMS  = ITEM_ELEMS + USER_ELEMS;  // 9,600,000

// ---------------- CSR build ----------------

__global__ __launch_bounds__(256) void hist_kernel(
    const int4* __restrict__ u4, const int4* __restrict__ i4,
    int* __restrict__ counts) {
  int q = blockIdx.x * 256 + threadIdx.x;
  if (q >= QEDGES) return;
  int4 u = u4[q];
  int4 it = i4[q];
  atomicAdd(&counts[u.x], 1);
  atomicAdd(&counts[u.y], 1);
  atomicAdd(&counts[u.z], 1);
  atomicAdd(&counts[u.w], 1);
  atomicAdd(&counts[N_USERS + it.x], 1);
  atomicAdd(&counts[N_USERS + it.y], 1);
  atomicAdd(&counts[N_USERS + it.z], 1);
  atomicAdd(&counts[N_USERS + it.w], 1);
}

// per-256-block exclusive scan; block sums out
__global__ __launch_bounds__(256) void scanA_kernel(
    const int* __restrict__ counts, int* __restrict__ row_ptr,
    int* __restrict__ blksums, int n) {
  __shared__ int sh[256];
  int t = threadIdx.x;
  int i = blockIdx.x * 256 + t;
  int v = (i < n) ? counts[i] : 0;
  int x = v;
  sh[t] = x; __syncthreads();
  for (int d = 1; d < 256; d <<= 1) {
    int add = (t >= d) ? sh[t - d] : 0;
    __syncthreads();
    x += add; sh[t] = x;
    __syncthreads();
  }
  if (i < n) row_ptr[i] = x - v;  // exclusive within block
  if (t == 255) blksums[blockIdx.x] = x;
}

// single-block exclusive scan of block sums (n2 <= 1024)
__global__ __launch_bounds__(1024) void scanB_kernel(int* __restrict__ blksums, int n2) {
  __shared__ int sh[1024];
  int t = threadIdx.x;
  int v = (t < n2) ? blksums[t] : 0;
  int x = v;
  sh[t] = x; __syncthreads();
  for (int d = 1; d < 1024; d <<= 1) {
    int add = (t >= d) ? sh[t - d] : 0;
    __syncthreads();
    x += add; sh[t] = x;
    __syncthreads();
  }
  if (t < n2) blksums[t] = x - v;  // exclusive
}

// add block offsets; init cursor; set terminator
__global__ __launch_bounds__(256) void scanC_kernel(
    int* __restrict__ row_ptr, const int* __restrict__ blksums,
    int* __restrict__ cursor, int n) {
  int i = blockIdx.x * 256 + threadIdx.x;
  if (i < n) {
    int p = row_ptr[i] + blksums[i >> 8];
    row_ptr[i] = p;
    cursor[i] = p;
  }
  if (i == 0) row_ptr[n] = NDIR;
}

// windowed scatter into packed CSR slots. Window = rows [pass*WROWS,
// (pass+1)*WROWS); each pass's blocks are contiguous in blockIdx so its
// ~4MB slot window is written while L2-resident. 4 edges/thread.
__global__ __launch_bounds__(256) void scatter_csr_win(
    const int4* __restrict__ u4, const int4* __restrict__ i4,
    const float4* __restrict__ w4, int* __restrict__ cursor,
    int2* __restrict__ csr) {
  int pass = blockIdx.x / BPP;
  int q = (blockIdx.x - pass * BPP) * 256 + threadIdx.x;
  if (q >= QEDGES) return;
  const int wlo = pass * WROWS;

  int4   u  = u4[q];
  int4   it = i4[q];
  float4 w  = w4[q];

#define PROC(UU, II, WW)                                             \
  {                                                                  \
    int ru = (UU), ri = N_USERS + (II);                              \
    int wb = __float_as_int(WW);                                     \
    if ((unsigned)(ru - wlo) < (unsigned)WROWS) {                    \
      int p = atomicAdd(&cursor[ru], 1);                             \
      csr[p] = make_int2((II), wb);                                  \
    }                                                                \
    if ((unsigned)(ri - wlo) < (unsigned)WROWS) {                    \
      int p = atomicAdd(&cursor[ri], 1);                             \
      csr[p] = make_int2((UU), wb);                                  \
    }                                                                \
  }
  PROC(u.x, it.x, w.x)
  PROC(u.y, it.y, w.y)
  PROC(u.z, it.z, w.z)
  PROC(u.w, it.w, w.w)
#undef PROC
}

// ---------------- per-layer fused gather ----------------
// One wave per destination row; lane = slot(2b) x chan16(4b); 4 edges in
// flight, butterfly-reduce slots. Epilogue fuses residual accumulation:
//   MODE 0 (layer 1):   dst = acc;  out = emb + acc
//   MODE 1 (mid layer): dst = acc;  out += acc
//   MODE 2 (last):                  out = (out + acc) * 1/(LAYERS+1)
template <int MODE>
__global__ __launch_bounds__(256) void gather_fused(
    const float* __restrict__ it_tab,  // gather-source item table
    const float* __restrict__ u_tab,   // gather-source user table
    float* __restrict__ dst,           // [it|u] layer output (MODE<2)
    float* __restrict__ out,           // [item_acc | user_acc]
    const int2* __restrict__ csr,
    const int* __restrict__ row_ptr) {
  int row = blockIdx.x * 4 + (threadIdx.x >> 6);
  if (row >= NROWS) return;
  int lane = threadIdx.x & 63;
  int slot = lane >> 4;          // 0..3
  int c4   = (lane & 15) * 4;    // channel offset 0..60

  const float* gtab;             // opposite-side table to gather from
  const float* erow = nullptr;   // dest-side input-emb row (MODE 0)
  float* drow = nullptr;
  float* orow;
  if (row < N_USERS) {
    gtab = it_tab;
    orow = out + ITEM_ELEMS + (long long)row * CH;
    if (MODE < 2)  drow = dst + ITEM_ELEMS + (long long)row * CH;
    if (MODE == 0) erow = u_tab + (long long)row * CH;  // u_tab==user_emb here
  } else {
    int r = row - N_USERS;
    gtab = u_tab;
    orow = out + (long long)r * CH;
    if (MODE < 2)  drow = dst + (long long)r * CH;
    if (MODE == 0) erow = it_tab + (long long)r * CH;   // it_tab==item_emb here
  }

  int beg = row_ptr[row], end = row_ptr[row + 1];
  float4 acc = make_float4(0.f, 0.f, 0.f, 0.f);
  for (int j = beg + slot; j < end; j += 4) {
    int2  e  = csr[j];
    float we = __int_as_float(e.y);
    float4 v = *(const float4*)(gtab + (long long)e.x * CH + c4);
    acc.x += we * v.x; acc.y += we * v.y;
    acc.z += we * v.z; acc.w += we * v.w;
  }
  for (int off = 16; off < 64; off <<= 1) {
    acc.x += __shfl_xor(acc.x, off, 64);
    acc.y += __shfl_xor(acc.y, off, 64);
    acc.z += __shfl_xor(acc.z, off, 64);
    acc.w += __shfl_xor(acc.w, off, 64);
  }
  if (slot == 0) {
    if (MODE == 0) {
      float4 e4 = *(const float4*)(erow + c4);
      *(float4*)(drow + c4) = acc;
      e4.x += acc.x; e4.y += acc.y; e4.z += acc.z; e4.w += acc.w;
      *(float4*)(orow + c4) = e4;
    } else if (MODE == 1) {
      float4 o = *(const float4*)(orow + c4);
      *(float4*)(drow + c4) = acc;
      o.x += acc.x; o.y += acc.y; o.z += acc.z; o.w += acc.w;
      *(float4*)(orow + c4) = o;
    } else {
      const float s = 1.0f / (LAYERS + 1);
      float4 o = *(const float4*)(orow + c4);
      o.x = (o.x + acc.x) * s; o.y = (o.y + acc.y) * s;
      o.z = (o.z + acc.z) * s; o.w = (o.w + acc.w) * s;
      *(float4*)(orow + c4) = o;
    }
  }
}

// ---------------- fallback (R1 atomic path) ----------------

__global__ __launch_bounds__(256) void atomic_scatter_kernel(
    const float* __restrict__ src, float* __restrict__ dst,
    const int* __restrict__ u_idx, const int* __restrict__ i_idx,
    const float* __restrict__ w) {
  long long tid = (long long)blockIdx.x * blockDim.x + threadIdx.x;
  int edge = (int)(tid >> 4);
  if (edge >= N_EDGES) return;
  int c = ((int)tid & 15) * 4;
  int ui = u_idx[edge], ii = i_idx[edge];
  float we = w[edge];
  float4 itv = *(const float4*)(src + (long long)ii * CH + c);
  float4 uv  = *(const float4*)(src + ITEM_ELEMS + (long long)ui * CH + c);
  float* ud = dst + ITEM_ELEMS + (long long)ui * CH + c;
  float* id = dst + (long long)ii * CH + c;
  unsafeAtomicAdd(ud + 0, we * itv.x);
  unsafeAtomicAdd(ud + 1, we * itv.y);
  unsafeAtomicAdd(ud + 2, we * itv.z);
  unsafeAtomicAdd(ud + 3, we * itv.w);
  unsafeAtomicAdd(id + 0, we * uv.x);
  unsafeAtomicAdd(id + 1, we * uv.y);
  unsafeAtomicAdd(id + 2, we * uv.z);
  unsafeAtomicAdd(id + 3, we * uv.w);
}

__global__ __launch_bounds__(256) void add_scale_kernel(
    float* __restrict__ acc, const float* __restrict__ add, float s, long long n4) {
  long long i = (long long)blockIdx.x * blockDim.x + threadIdx.x;
  if (i >= n4) return;
  float4 a = ((const float4*)acc)[i];
  float4 b = ((const float4*)add)[i];
  a.x = (a.x + b.x) * s;
  a.y = (a.y + b.y) * s;
  a.z = (a.z + b.z) * s;
  a.w = (a.w + b.w) * s;
  ((float4*)acc)[i] = a;
}

extern "C" void kernel_launch(void* const* d_in, const int* in_sizes, int n_in,
                              void* d_out, int out_size, void* d_ws, size_t ws_size,
                              hipStream_t stream) {
  const float* user_emb = (const float*)d_in[1];
  const float* item_emb = (const float*)d_in[2];
  const int*   edges    = (const int*)d_in[3];
  const int*   u_idx    = edges;            // row 0
  const int*   i_idx    = edges + N_EDGES;  // row 1
  const float* w        = (const float*)d_in[4];

  float* out = (float*)d_out;  // [item_acc | user_acc]

  // workspace layout (4B units)
  float* buf_a   = (float*)d_ws;                 // TOT_ELEMS
  float* buf_b   = buf_a + TOT_ELEMS;            // TOT_ELEMS
  int2*  csr     = (int2*)(buf_b + TOT_ELEMS);   // NDIR int2
  int*   counts  = (int*)(csr + NDIR);           // NROWS
  int*   row_ptr = counts + NROWS;               // NROWS + 1
  int*   cursor  = row_ptr + NROWS + 1;          // NROWS
  int*   blksums = cursor + NROWS;               // 1024
  const size_t needed =
      ((size_t)2 * TOT_ELEMS + 2 * (size_t)NDIR + 3 * (size_t)NROWS + 1 + 1024) * 4;

  if (ws_size >= needed) {
    // ---- CSR build (once per call) ----
    hipMemsetAsync(counts, 0, (size_t)NROWS * sizeof(int), stream);
    const int qblocks = (QEDGES + 255) / 256;  // 1954
    hist_kernel<<<qblocks, 256, 0, stream>>>(
        (const int4*)u_idx, (const int4*)i_idx, counts);
    const int nblocksA = (NROWS + 255) / 256;  // 587 <= 1024
    scanA_kernel<<<nblocksA, 256, 0, stream>>>(counts, row_ptr, blksums, NROWS);
    scanB_kernel<<<1, 1024, 0, stream>>>(blksums, nblocksA);
    scanC_kernel<<<nblocksA, 256, 0, stream>>>(row_ptr, blksums, cursor, NROWS);
    scatter_csr_win<<<PASSES * BPP, 256, 0, stream>>>(
        (const int4*)u_idx, (const int4*)i_idx, (const float4*)w, cursor, csr);

    // ---- layers (gather + fused residual) ----
    const int gather_blocks = (NROWS + 3) / 4;  // 4 rows (waves) per block
    // L1: gather from input tables; out = emb + l1; buf_a = l1
    gather_fused<0><<<gather_blocks, 256, 0, stream>>>(
        item_emb, user_emb, buf_a, out, csr, row_ptr);
    // L2: gather from buf_a; out += l2; buf_b = l2
    gather_fused<1><<<gather_blocks, 256, 0, stream>>>(
        buf_a, buf_a + ITEM_ELEMS, buf_b, out, csr, row_ptr);
    // L3: gather from buf_b; out = (out + l3) * 0.25
    gather_fused<2><<<gather_blocks, 256, 0, stream>>>(
        buf_b, buf_b + ITEM_ELEMS, nullptr, out, csr, row_ptr);
  } else {
    // ---- fallback: R1 atomic scatter ----
    const size_t item_bytes = (size_t)ITEM_ELEMS * sizeof(float);
    const size_t user_bytes = (size_t)USER_ELEMS * sizeof(float);
    hipMemcpyAsync(buf_a,              item_emb, item_bytes, hipMemcpyDeviceToDevice, stream);
    hipMemcpyAsync(buf_a + ITEM_ELEMS, user_emb, user_bytes, hipMemcpyDeviceToDevice, stream);
    hipMemcpyAsync(out,                item_emb, item_bytes, hipMemcpyDeviceToDevice, stream);
    hipMemcpyAsync(out + ITEM_ELEMS,   user_emb, user_bytes, hipMemcpyDeviceToDevice, stream);
    const long long st = (long long)N_EDGES * 16;
    const int sb = (int)((st + 255) / 256);
    const long long n4 = TOT_ELEMS / 4;
    const int add_blocks = (int)((n4 + 255) / 256);
    float* src = buf_a;
    float* dst = buf_b;
    for (int l = 0; l < LAYERS; ++l) {
      hipMemsetAsync(dst, 0, (size_t)TOT_ELEMS * sizeof(float), stream);
      atomic_scatter_kernel<<<sb, 256, 0, stream>>>(src, dst, u_idx, i_idx, w);
      const float s = (l == LAYERS - 1) ? (1.0f / (LAYERS + 1)) : 1.0f;
      add_scale_kernel<<<add_blocks, 256, 0, stream>>>(out, dst, s, n4);
      float* t = src; src = dst; dst = t;
    }
  }
}

// Round 5
// 834.453 us; speedup vs baseline: 1.2683x; 1.0717x over previous
//
#include <hip/hip_runtime.h>

// AttnHGCN.forward_ui — 3-layer bipartite LightGCN-style propagation.
// R5: (a) XCD-pinned scatter windows: pass = blockIdx % 8, so (per the
//     round-robin blockIdx->XCD heuristic) all stores to one ~4MB CSR slot
//     window flow through ONE XCD's L2 — R4 showed temporal windowing alone
//     can't coalesce partial-line stores across 8 non-coherent L2s
//     (WRITE_SIZE stayed 247MB).
//     (b) gather adjacency loop unrolled x2: 8 outstanding 256B row gathers
//     per wave (gathers looked latency-bound at ~6.3TB/s over L3 data).

constexpr int N_USERS = 100000;
constexpr int N_ITEMS = 50000;
constexpr int CH      = 64;
constexpr int N_EDGES = 2000000;
constexpr int LAYERS  = 3;
constexpr int NROWS   = N_USERS + N_ITEMS;          // 150000 combined dest rows
constexpr int NDIR    = 2 * N_EDGES;                // 4M directed edges

constexpr int PASSES  = 8;
constexpr int WROWS   = NROWS / PASSES;             // 18750 rows per window
constexpr int QEDGES  = N_EDGES / 4;                // 500000 int4 edge-quads
constexpr int BPP     = (QEDGES + 255) / 256;       // blocks per pass = 1954

constexpr long long ITEM_ELEMS = (long long)N_ITEMS * CH;  // 3,200,000
constexpr long long USER_ELEMS = (long long)N_USERS * CH;  // 6,400,000
constexpr long long TOT_ELEMS  = ITEM_ELEMS + USER_ELEMS;  // 9,600,000

// ---------------- CSR build ----------------

__global__ __launch_bounds__(256) void hist_kernel(
    const int4* __restrict__ u4, const int4* __restrict__ i4,
    int* __restrict__ counts) {
  int q = blockIdx.x * 256 + threadIdx.x;
  if (q >= QEDGES) return;
  int4 u = u4[q];
  int4 it = i4[q];
  atomicAdd(&counts[u.x], 1);
  atomicAdd(&counts[u.y], 1);
  atomicAdd(&counts[u.z], 1);
  atomicAdd(&counts[u.w], 1);
  atomicAdd(&counts[N_USERS + it.x], 1);
  atomicAdd(&counts[N_USERS + it.y], 1);
  atomicAdd(&counts[N_USERS + it.z], 1);
  atomicAdd(&counts[N_USERS + it.w], 1);
}

// per-256-block exclusive scan; block sums out
__global__ __launch_bounds__(256) void scanA_kernel(
    const int* __restrict__ counts, int* __restrict__ row_ptr,
    int* __restrict__ blksums, int n) {
  __shared__ int sh[256];
  int t = threadIdx.x;
  int i = blockIdx.x * 256 + t;
  int v = (i < n) ? counts[i] : 0;
  int x = v;
  sh[t] = x; __syncthreads();
  for (int d = 1; d < 256; d <<= 1) {
    int add = (t >= d) ? sh[t - d] : 0;
    __syncthreads();
    x += add; sh[t] = x;
    __syncthreads();
  }
  if (i < n) row_ptr[i] = x - v;  // exclusive within block
  if (t == 255) blksums[blockIdx.x] = x;
}

// single-block exclusive scan of block sums (n2 <= 1024)
__global__ __launch_bounds__(1024) void scanB_kernel(int* __restrict__ blksums, int n2) {
  __shared__ int sh[1024];
  int t = threadIdx.x;
  int v = (t < n2) ? blksums[t] : 0;
  int x = v;
  sh[t] = x; __syncthreads();
  for (int d = 1; d < 1024; d <<= 1) {
    int add = (t >= d) ? sh[t - d] : 0;
    __syncthreads();
    x += add; sh[t] = x;
    __syncthreads();
  }
  if (t < n2) blksums[t] = x - v;  // exclusive
}

// add block offsets; init cursor; set terminator
__global__ __launch_bounds__(256) void scanC_kernel(
    int* __restrict__ row_ptr, const int* __restrict__ blksums,
    int* __restrict__ cursor, int n) {
  int i = blockIdx.x * 256 + threadIdx.x;
  if (i < n) {
    int p = row_ptr[i] + blksums[i >> 8];
    row_ptr[i] = p;
    cursor[i] = p;
  }
  if (i == 0) row_ptr[n] = NDIR;
}

// XCD-pinned windowed scatter. pass = blockIdx % PASSES so (round-robin
// blockIdx->XCD heuristic) window w's ~4MB of slots is written only by
// XCD w: partial-line stores coalesce in that single L2 before writeback.
__global__ __launch_bounds__(256) void scatter_csr_win(
    const int4* __restrict__ u4, const int4* __restrict__ i4,
    const float4* __restrict__ w4, int* __restrict__ cursor,
    int2* __restrict__ csr) {
  int pass = blockIdx.x % PASSES;
  int q = (blockIdx.x / PASSES) * 256 + threadIdx.x;
  if (q >= QEDGES) return;
  const int wlo = pass * WROWS;

  int4   u  = u4[q];
  int4   it = i4[q];
  float4 w  = w4[q];

#define PROC(UU, II, WW)                                             \
  {                                                                  \
    int ru = (UU), ri = N_USERS + (II);                              \
    int wb = __float_as_int(WW);                                     \
    if ((unsigned)(ru - wlo) < (unsigned)WROWS) {                    \
      int p = atomicAdd(&cursor[ru], 1);                             \
      csr[p] = make_int2((II), wb);                                  \
    }                                                                \
    if ((unsigned)(ri - wlo) < (unsigned)WROWS) {                    \
      int p = atomicAdd(&cursor[ri], 1);                             \
      csr[p] = make_int2((UU), wb);                                  \
    }                                                                \
  }
  PROC(u.x, it.x, w.x)
  PROC(u.y, it.y, w.y)
  PROC(u.z, it.z, w.z)
  PROC(u.w, it.w, w.w)
#undef PROC
}

// ---------------- per-layer fused gather ----------------
// One wave per destination row; lane = slot(2b) x chan16(4b); adjacency loop
// unrolled x2 -> 8 edges (8x256B gathers) in flight per wave; butterfly-
// reduce slots. Epilogue fuses residual accumulation:
//   MODE 0 (layer 1):   dst = acc;  out = emb + acc
//   MODE 1 (mid layer): dst = acc;  out += acc
//   MODE 2 (last):                  out = (out + acc) * 1/(LAYERS+1)
template <int MODE>
__global__ __launch_bounds__(256) void gather_fused(
    const float* __restrict__ it_tab,  // gather-source item table
    const float* __restrict__ u_tab,   // gather-source user table
    float* __restrict__ dst,           // [it|u] layer output (MODE<2)
    float* __restrict__ out,           // [item_acc | user_acc]
    const int2* __restrict__ csr,
    const int* __restrict__ row_ptr) {
  int row = blockIdx.x * 4 + (threadIdx.x >> 6);
  if (row >= NROWS) return;
  int lane = threadIdx.x & 63;
  int slot = lane >> 4;          // 0..3
  int c4   = (lane & 15) * 4;    // channel offset 0..60

  const float* gtab;             // opposite-side table to gather from
  const float* erow = nullptr;   // dest-side input-emb row (MODE 0)
  float* drow = nullptr;
  float* orow;
  if (row < N_USERS) {
    gtab = it_tab;
    orow = out + ITEM_ELEMS + (long long)row * CH;
    if (MODE < 2)  drow = dst + ITEM_ELEMS + (long long)row * CH;
    if (MODE == 0) erow = u_tab + (long long)row * CH;  // u_tab==user_emb here
  } else {
    int r = row - N_USERS;
    gtab = u_tab;
    orow = out + (long long)r * CH;
    if (MODE < 2)  drow = dst + (long long)r * CH;
    if (MODE == 0) erow = it_tab + (long long)r * CH;   // it_tab==item_emb here
  }

  int beg = row_ptr[row], end = row_ptr[row + 1];
  float4 acc = make_float4(0.f, 0.f, 0.f, 0.f);
  int j = beg + slot;
  // unrolled x2: two independent (csr, row) load pairs in flight
  for (; j + 4 < end; j += 8) {
    int2  e0 = csr[j];
    int2  e1 = csr[j + 4];
    float4 v0 = *(const float4*)(gtab + (long long)e0.x * CH + c4);
    float4 v1 = *(const float4*)(gtab + (long long)e1.x * CH + c4);
    float w0 = __int_as_float(e0.y);
    float w1 = __int_as_float(e1.y);
    acc.x += w0 * v0.x; acc.y += w0 * v0.y;
    acc.z += w0 * v0.z; acc.w += w0 * v0.w;
    acc.x += w1 * v1.x; acc.y += w1 * v1.y;
    acc.z += w1 * v1.z; acc.w += w1 * v1.w;
  }
  if (j < end) {
    int2  e  = csr[j];
    float we = __int_as_float(e.y);
    float4 v = *(const float4*)(gtab + (long long)e.x * CH + c4);
    acc.x += we * v.x; acc.y += we * v.y;
    acc.z += we * v.z; acc.w += we * v.w;
  }
  for (int off = 16; off < 64; off <<= 1) {
    acc.x += __shfl_xor(acc.x, off, 64);
    acc.y += __shfl_xor(acc.y, off, 64);
    acc.z += __shfl_xor(acc.z, off, 64);
    acc.w += __shfl_xor(acc.w, off, 64);
  }
  if (slot == 0) {
    if (MODE == 0) {
      float4 e4 = *(const float4*)(erow + c4);
      *(float4*)(drow + c4) = acc;
      e4.x += acc.x; e4.y += acc.y; e4.z += acc.z; e4.w += acc.w;
      *(float4*)(orow + c4) = e4;
    } else if (MODE == 1) {
      float4 o = *(const float4*)(orow + c4);
      *(float4*)(drow + c4) = acc;
      o.x += acc.x; o.y += acc.y; o.z += acc.z; o.w += acc.w;
      *(float4*)(orow + c4) = o;
    } else {
      const float s = 1.0f / (LAYERS + 1);
      float4 o = *(const float4*)(orow + c4);
      o.x = (o.x + acc.x) * s; o.y = (o.y + acc.y) * s;
      o.z = (o.z + acc.z) * s; o.w = (o.w + acc.w) * s;
      *(float4*)(orow + c4) = o;
    }
  }
}

// ---------------- fallback (R1 atomic path) ----------------

__global__ __launch_bounds__(256) void atomic_scatter_kernel(
    const float* __restrict__ src, float* __restrict__ dst,
    const int* __restrict__ u_idx, const int* __restrict__ i_idx,
    const float* __restrict__ w) {
  long long tid = (long long)blockIdx.x * blockDim.x + threadIdx.x;
  int edge = (int)(tid >> 4);
  if (edge >= N_EDGES) return;
  int c = ((int)tid & 15) * 4;
  int ui = u_idx[edge], ii = i_idx[edge];
  float we = w[edge];
  float4 itv = *(const float4*)(src + (long long)ii * CH + c);
  float4 uv  = *(const float4*)(src + ITEM_ELEMS + (long long)ui * CH + c);
  float* ud = dst + ITEM_ELEMS + (long long)ui * CH + c;
  float* id = dst + (long long)ii * CH + c;
  unsafeAtomicAdd(ud + 0, we * itv.x);
  unsafeAtomicAdd(ud + 1, we * itv.y);
  unsafeAtomicAdd(ud + 2, we * itv.z);
  unsafeAtomicAdd(ud + 3, we * itv.w);
  unsafeAtomicAdd(id + 0, we * uv.x);
  unsafeAtomicAdd(id + 1, we * uv.y);
  unsafeAtomicAdd(id + 2, we * uv.z);
  unsafeAtomicAdd(id + 3, we * uv.w);
}

__global__ __launch_bounds__(256) void add_scale_kernel(
    float* __restrict__ acc, const float* __restrict__ add, float s, long long n4) {
  long long i = (long long)blockIdx.x * blockDim.x + threadIdx.x;
  if (i >= n4) return;
  float4 a = ((const float4*)acc)[i];
  float4 b = ((const float4*)add)[i];
  a.x = (a.x + b.x) * s;
  a.y = (a.y + b.y) * s;
  a.z = (a.z + b.z) * s;
  a.w = (a.w + b.w) * s;
  ((float4*)acc)[i] = a;
}

extern "C" void kernel_launch(void* const* d_in, const int* in_sizes, int n_in,
                              void* d_out, int out_size, void* d_ws, size_t ws_size,
                              hipStream_t stream) {
  const float* user_emb = (const float*)d_in[1];
  const float* item_emb = (const float*)d_in[2];
  const int*   edges    = (const int*)d_in[3];
  const int*   u_idx    = edges;            // row 0
  const int*   i_idx    = edges + N_EDGES;  // row 1
  const float* w        = (const float*)d_in[4];

  float* out = (float*)d_out;  // [item_acc | user_acc]

  // workspace layout (4B units)
  float* buf_a   = (float*)d_ws;                 // TOT_ELEMS
  float* buf_b   = buf_a + TOT_ELEMS;            // TOT_ELEMS
  int2*  csr     = (int2*)(buf_b + TOT_ELEMS);   // NDIR int2
  int*   counts  = (int*)(csr + NDIR);           // NROWS
  int*   row_ptr = counts + NROWS;               // NROWS + 1
  int*   cursor  = row_ptr + NROWS + 1;          // NROWS
  int*   blksums = cursor + NROWS;               // 1024
  const size_t needed =
      ((size_t)2 * TOT_ELEMS + 2 * (size_t)NDIR + 3 * (size_t)NROWS + 1 + 1024) * 4;

  if (ws_size >= needed) {
    // ---- CSR build (once per call) ----
    hipMemsetAsync(counts, 0, (size_t)NROWS * sizeof(int), stream);
    const int qblocks = (QEDGES + 255) / 256;  // 1954
    hist_kernel<<<qblocks, 256, 0, stream>>>(
        (const int4*)u_idx, (const int4*)i_idx, counts);
    const int nblocksA = (NROWS + 255) / 256;  // 587 <= 1024
    scanA_kernel<<<nblocksA, 256, 0, stream>>>(counts, row_ptr, blksums, NROWS);
    scanB_kernel<<<1, 1024, 0, stream>>>(blksums, nblocksA);
    scanC_kernel<<<nblocksA, 256, 0, stream>>>(row_ptr, blksums, cursor, NROWS);
    scatter_csr_win<<<PASSES * BPP, 256, 0, stream>>>(
        (const int4*)u_idx, (const int4*)i_idx, (const float4*)w, cursor, csr);

    // ---- layers (gather + fused residual) ----
    const int gather_blocks = (NROWS + 3) / 4;  // 4 rows (waves) per block
    // L1: gather from input tables; out = emb + l1; buf_a = l1
    gather_fused<0><<<gather_blocks, 256, 0, stream>>>(
        item_emb, user_emb, buf_a, out, csr, row_ptr);
    // L2: gather from buf_a; out += l2; buf_b = l2
    gather_fused<1><<<gather_blocks, 256, 0, stream>>>(
        buf_a, buf_a + ITEM_ELEMS, buf_b, out, csr, row_ptr);
    // L3: gather from buf_b; out = (out + l3) * 0.25
    gather_fused<2><<<gather_blocks, 256, 0, stream>>>(
        buf_b, buf_b + ITEM_ELEMS, nullptr, out, csr, row_ptr);
  } else {
    // ---- fallback: R1 atomic scatter ----
    const size_t item_bytes = (size_t)ITEM_ELEMS * sizeof(float);
    const size_t user_bytes = (size_t)USER_ELEMS * sizeof(float);
    hipMemcpyAsync(buf_a,              item_emb, item_bytes, hipMemcpyDeviceToDevice, stream);
    hipMemcpyAsync(buf_a + ITEM_ELEMS, user_emb, user_bytes, hipMemcpyDeviceToDevice, stream);
    hipMemcpyAsync(out,                item_emb, item_bytes, hipMemcpyDeviceToDevice, stream);
    hipMemcpyAsync(out + ITEM_ELEMS,   user_emb, user_bytes, hipMemcpyDeviceToDevice, stream);
    const long long st = (long long)N_EDGES * 16;
    const int sb = (int)((st + 255) / 256);
    const long long n4 = TOT_ELEMS / 4;
    const int add_blocks = (int)((n4 + 255) / 256);
    float* src = buf_a;
    float* dst = buf_b;
    for (int l = 0; l < LAYERS; ++l) {
      hipMemsetAsync(dst, 0, (size_t)TOT_ELEMS * sizeof(float), stream);
      atomic_scatter_kernel<<<sb, 256, 0, stream>>>(src, dst, u_idx, i_idx, w);
      const float s = (l == LAYERS - 1) ? (1.0f / (LAYERS + 1)) : 1.0f;
      add_scale_kernel<<<add_blocks, 256, 0, stream>>>(out, dst, s, n4);
      float* t = src; src = dst; dst = t;
    }
  }
}